// Round 8
// baseline (478.956 us; speedup 1.0000x reference)
//
#include <hip/hip_runtime.h>
#include <math.h>

// ---- output layout ----
#define OFF_IMU  0
#define OFF_ATOM 19660800
#define OFF_SEG  20160000
#define OFF_FC   20659200
#define OFF_FL   20691968

// ---- ws layout (4-byte elements) ----
#define WS_BRIDGE 0        // 32768 floats  (8192 x 4)
#define WS_TR     32768    // 262144 floats (8192 x 32)
#define WS_SEGID  294912   // 8192 ints
#define WS_ENDS   303104   // 4160 ints
#define WS_STARTS 307264   // 4160 ints
#define WS_NK     311424   // 32 ints

static __device__ __forceinline__ int imin(int a, int b) { return a < b ? a : b; }
static __device__ __forceinline__ int imax(int a, int b) { return a > b ? a : b; }

// v_pk_fma_f32: S(.x,.y) += W(.x,.y) * broadcast(X.lo or X.hi)
#define PK_FMA_LO(S, W, X) \
    asm("v_pk_fma_f32 %0, %1, %2, %0 op_sel:[0,0,0] op_sel_hi:[1,0,1]" \
        : "+v"(S) : "v"(W), "v"(X))
#define PK_FMA_HI(S, W, X) \
    asm("v_pk_fma_f32 %0, %1, %2, %0 op_sel:[0,1,0] op_sel_hi:[1,1,1]" \
        : "+v"(S) : "v"(W), "v"(X))

union F4 { float4 q; float2 h[2]; };

// load one 4-chunk (6 rows x float4) from LDS; imm-offset ds_read_b128
__device__ __forceinline__ void load_chunk(const float* p,
                                           float2 (&D01)[6], float2 (&D23)[6])
{
#pragma unroll
    for (int ic = 0; ic < 6; ++ic) {
        const F4 f = *(const F4*)(p + ic * 404);
        D01[ic] = f.h[0]; D23[ic] = f.h[1];
    }
}

// conv math for one 4-chunk. Two passes: S0/S1 touch only C (prefetch-safe),
// S2/S3 touch N01 (freshly loaded) last.
__device__ __forceinline__ void math_chunk(
    const float2 (&C01)[6], const float2 (&C23)[6], const float2 (&N01)[6],
    const float2 (&W2)[18], const float2 cb2,
    float2& R0, float2& R1, float2& R2, float2& R3)
{
    float2 S0 = cb2, S1 = cb2, S2 = cb2, S3 = cb2;
#pragma unroll
    for (int ic = 0; ic < 6; ++ic) {
        const float2 w0 = W2[ic*3+0], w1 = W2[ic*3+1], w2 = W2[ic*3+2];
        PK_FMA_LO(S0, w0, C01[ic]); PK_FMA_HI(S0, w1, C01[ic]); PK_FMA_LO(S0, w2, C23[ic]);
        PK_FMA_HI(S1, w0, C01[ic]); PK_FMA_LO(S1, w1, C23[ic]); PK_FMA_HI(S1, w2, C23[ic]);
    }
#pragma unroll
    for (int ic = 0; ic < 6; ++ic) {
        const float2 w0 = W2[ic*3+0], w1 = W2[ic*3+1], w2 = W2[ic*3+2];
        PK_FMA_LO(S2, w0, C23[ic]); PK_FMA_HI(S2, w1, C23[ic]); PK_FMA_LO(S2, w2, N01[ic]);
        PK_FMA_HI(S3, w0, C23[ic]); PK_FMA_LO(S3, w1, N01[ic]); PK_FMA_HI(S3, w2, N01[ic]);
    }
    R0 = S0; R1 = S1; R2 = S2; R3 = S3;
}

// ============================================================================
// K1: conv1d(6->32,k=3,VALID) + ReLU + half-mean-pool + bridge sigmoid MLP
// 2048 blocks x 256 threads; 4 samples/block, one WAVE per sample.
// Lane l: oc-pair pr=l&15, half hg=(l>>4)&1, quarter q=l>>5; packed fp32 math.
// A/B ping-pong chunk pipeline (no register copies, 1-chunk prefetch depth),
// fixed base pointer + fully-unrolled loop -> all ds_read offsets immediate.
// ============================================================================
__global__ __launch_bounds__(256, 4) void k1_conv_bridge(
    const float* __restrict__ x, const float* __restrict__ conv_w,
    const float* __restrict__ conv_b, const float* __restrict__ W_b1,
    const float* __restrict__ b_b1, float* __restrict__ bridge)
{
    __shared__ __align__(16) float xs[4][2424];  // [smp][ic*404 + t]; 400..403 zeroed
    __shared__ float pooledL[4][64];
    const int tid = threadIdx.x;
    const int n0 = blockIdx.x * 4;

    const int wv = tid >> 6;           // wave = sample
    const int l  = tid & 63;
    const int pr = l & 15;             // oc pair: 2pr, 2pr+1
    const int hg = (l >> 4) & 1;       // pooling half
    const int q  = l >> 5;             // quarter within half

    // weight pairs (loop-invariant): W2[j] = (w[2pr][j], w[2pr+1][j])
    float2 W2[18];
    {
        const float* wa = conv_w + (2 * pr) * 18;
        const float* wb = wa + 18;
#pragma unroll
        for (int j = 0; j < 18; ++j) W2[j] = make_float2(wa[j], wb[j]);
    }
    const float2 cb2 = make_float2(conv_b[2 * pr], conv_b[2 * pr + 1]);

    // stage 4 samples of x into LDS (coalesced float4)
    const float* xn = x + (size_t)n0 * 2400;
    for (int i = tid; i < 2400; i += 256) {
        const float4 v = ((const float4*)xn)[i];
        const int smp = i / 600;
        const int r = i - smp * 600;
        const int ic = r / 100, t4 = (r - ic * 100) * 4;
        *(float4*)&xs[smp][ic * 404 + t4] = v;
    }
    if (tid < 96) {                    // zero pads so tail multiplies stay finite
        const int smp = tid / 24, r = tid - smp * 24;
        xs[smp][(r >> 2) * 404 + 400 + (r & 3)] = 0.0f;
    }
    __syncthreads();

    const float* rb = &xs[wv][hg * 200 + q * 100];   // fixed; all offsets imm
    float2 accM = make_float2(0.0f, 0.0f);
    float2 extra = make_float2(0.0f, 0.0f);

    float2 A01[6], A23[6], B01[6], B23[6];
    load_chunk(rb, A01, A23);          // chunk 0
    load_chunk(rb + 4, B01, B23);      // chunk 1

    float2 R0, R1, R2, R3;
    // 24 body chunks as 12 double-iterations; roles alternate (no copies)
#pragma unroll
    for (int d = 0; d < 12; ++d) {
        math_chunk(A01, A23, B01, W2, cb2, R0, R1, R2, R3);   // chunk 2d
        load_chunk(rb + (2 * d + 2) * 4, A01, A23);           // -> chunk 2d+2
        accM.x += fmaxf(R0.x,0.f)+fmaxf(R1.x,0.f)+fmaxf(R2.x,0.f)+fmaxf(R3.x,0.f);
        accM.y += fmaxf(R0.y,0.f)+fmaxf(R1.y,0.f)+fmaxf(R2.y,0.f)+fmaxf(R3.y,0.f);

        math_chunk(B01, B23, A01, W2, cb2, R0, R1, R2, R3);   // chunk 2d+1
        load_chunk(rb + (2 * d + 3) * 4, B01, B23);           // -> chunk 2d+3
        accM.x += fmaxf(R0.x,0.f)+fmaxf(R1.x,0.f)+fmaxf(R2.x,0.f)+fmaxf(R3.x,0.f);
        accM.y += fmaxf(R0.y,0.f)+fmaxf(R1.y,0.f)+fmaxf(R2.y,0.f)+fmaxf(R3.y,0.f);
    }
    // after loop: A = chunk 24, B = chunk 25 (q1hg1's chunk25 lands in the pad)

    // tail chunk 24 (t = qbase+96..99):
    //  q0: all 4 valid; q1,hg0: r0-r2 valid, r3 -> extra (t=199 belongs to half1);
    //  q1,hg1: r0,r1 valid (t=396,397); r2,r3 invalid (pads keep math finite)
    math_chunk(A01, A23, B01, W2, cb2, R0, R1, R2, R3);
    {
        const float r0x = fmaxf(R0.x,0.f), r0y = fmaxf(R0.y,0.f);
        const float r1x = fmaxf(R1.x,0.f), r1y = fmaxf(R1.y,0.f);
        const float r2x = fmaxf(R2.x,0.f), r2y = fmaxf(R2.y,0.f);
        const float r3x = fmaxf(R3.x,0.f), r3y = fmaxf(R3.y,0.f);
        if (q == 0) {
            accM.x += r0x + r1x + r2x + r3x;
            accM.y += r0y + r1y + r2y + r3y;
        } else if (hg == 0) {
            accM.x += r0x + r1x + r2x;  extra.x = r3x;
            accM.y += r0y + r1y + r2y;  extra.y = r3y;
        } else {
            accM.x += r0x + r1x;
            accM.y += r0y + r1y;
        }
    }

    // merge quarters (xor32) then route the t=199 extra (q1,hg0)->(q1,hg1)
    float2 tot;
    tot.x = accM.x + __shfl_xor(accM.x, 32);
    tot.y = accM.y + __shfl_xor(accM.y, 32);
    const float exx = __shfl_xor(extra.x, 16);
    const float exy = __shfl_xor(extra.y, 16);
    if (hg) { tot.x += exx; tot.y += exy; }
    if (q) {                           // q1 lanes hold complete (pr,hg) totals
        pooledL[wv][(2 * pr + 0) * 2 + hg] = tot.x * (1.0f / 199.0f);
        pooledL[wv][(2 * pr + 1) * 2 + hg] = tot.y * (1.0f / 199.0f);
    }
    __syncthreads();

    // bridge MLP: all 256 threads; sample = tid>>6, feature f = tid&63
    {
        const int s2 = tid >> 6, f = tid & 63;
        const float v = pooledL[s2][f];
        const float4 wb = *(const float4*)(W_b1 + f * 4);
        float p0 = v * wb.x, p1 = v * wb.y, p2 = v * wb.z, p3 = v * wb.w;
#pragma unroll
        for (int off = 1; off < 64; off <<= 1) {
            p0 += __shfl_xor(p0, off, 64);
            p1 += __shfl_xor(p1, off, 64);
            p2 += __shfl_xor(p2, off, 64);
            p3 += __shfl_xor(p3, off, 64);
        }
        if (f == 0) {
            float* bp = bridge + (size_t)(n0 + s2) * 4;
            bp[0] = 1.0f / (1.0f + __expf(-(p0 + b_b1[0])));
            bp[1] = 1.0f / (1.0f + __expf(-(p1 + b_b1[1])));
            bp[2] = 1.0f / (1.0f + __expf(-(p2 + b_b1[2])));
            bp[3] = 1.0f / (1.0f + __expf(-(p3 + b_b1[3])));
        }
    }
}

// ============================================================================
// K23: forcast + masked floss (to d_out) fused with per-batch segmentation.
// one block per b (32 x 256)
// ============================================================================
__global__ __launch_bounds__(256) void k23_forcast_seg(
    const float* __restrict__ bridge, const float* __restrict__ imu_mask,
    const float* __restrict__ W_fc, const float* __restrict__ b_fc,
    const int* __restrict__ imu_len, float* __restrict__ out,
    int* __restrict__ segid_ws, int* __restrict__ ends_ws,
    int* __restrict__ starts_ws, int* __restrict__ nk_ws)
{
    const int b = blockIdx.x, tid = threadIdx.x;
    const int n = b * 256 + tid;
    __shared__ float fl[256];
    __shared__ float sel[256];
    __shared__ float sp[256];
    __shared__ int pk[256];
    __shared__ int sc[2][256];
    __shared__ int kpl[256];

    // ---- forcast + floss ----
    float sh[4], cur[4];
#pragma unroll
    for (int j = 0; j < 4; ++j) {
        sh[j] = (tid == 0) ? 0.0f : bridge[(n - 1) * 4 + j];
        cur[j] = bridge[n * 4 + j];
    }
    const float fm = ((tid == 0) ? 0.0f : 1.0f) * imu_mask[n];
    float flv = 0.0f;
#pragma unroll
    for (int j = 0; j < 4; ++j) {
        float f = b_fc[j];
#pragma unroll
        for (int i = 0; i < 4; ++i) f = fmaf(sh[i], W_fc[i * 4 + j], f);
        out[OFF_FC + n * 4 + j] = f;
        const float d = (f - cur[j]) * fm;
        flv = fmaf(d, d, flv);
    }
    flv *= 0.25f;
    const bool lm = (tid >= 2) && (tid < 254);
    flv = (flv > 0.001f && lm) ? flv : 0.0f;
    out[OFF_FL + n] = flv;

    // ---- segmentation ----
    fl[tid] = flv;
    sp[tid] = 0.0f;
    __syncthreads();
    if (tid < 64) {                       // sel: windows of 4, first-max
        const int base = tid * 4;
        float m = fl[base]; int idx = 0;
#pragma unroll
        for (int i = 1; i < 4; ++i) { float v = fl[base + i]; if (v > m) { m = v; idx = i; } }
#pragma unroll
        for (int i = 0; i < 4; ++i) sel[base + i] = (i == idx) ? m : 0.0f;
    }
    __syncthreads();
    if (tid < 63) {                       // sel2 on sel[2:254), 63 windows of 4
        const int base = 2 + tid * 4;
        float m = sel[base]; int idx = 0;
#pragma unroll
        for (int i = 1; i < 4; ++i) { float v = sel[base + i]; if (v > m) { m = v; idx = i; } }
        sp[base + idx] = (m > 0.0f) ? 1.0f : 0.0f;
    }
    __syncthreads();
    int last = (int)rintf((float)imu_len[b] * (1.0f / 256.0f));  // half-even
    last = imin(imax(last, 2), 256);
    const int point = ((sp[tid] > 0.0f) && (tid < last)) ? 1 : 0;
    pk[tid] = point;
    __syncthreads();
    const int pnext = (tid < 255) ? pk[tid + 1] : 0;
    const int bnd = pnext | ((tid + 1 == last) ? 1 : 0);
    const int kept = (point && !bnd) ? 1 : 0;
    __syncthreads();
    sc[0][tid] = kept;
    __syncthreads();
    int src = 0;                          // Hillis-Steele inclusive scan
    for (int off = 1; off < 256; off <<= 1) {
        const int v = sc[src][tid] + ((tid >= off) ? sc[src][tid - off] : 0);
        sc[src ^ 1][tid] = v;
        __syncthreads();
        src ^= 1;
    }
    const int myid = sc[src][tid];
    segid_ws[b * 256 + tid] = myid;
    const int nk = sc[src][255];
    if (kept) kpl[myid - 1] = tid;
    __syncthreads();
    if (tid < 130) {
        ends_ws[b * 130 + tid] = (tid < nk) ? kpl[tid] : last;
        starts_ws[b * 130 + tid] = (tid == 0) ? 0 : ((tid - 1 < nk) ? kpl[tid - 1] : last);
    }
    if (tid == 0) nk_ws[b] = nk;
}

// ============================================================================
// K4: segment-masked attention (DM=4, 2 heads) + transformer block + tr_out
// grid 256 = (b, 32-query chunk), 256 threads: 8 j-groups x 32 queries,
// LDS online-softmax merge. NOTE hb[b,s] = bridge[s*32 + b] (scrambled).
// exp() only evaluated with argument <= 0 (select, never mask-multiply).
// ============================================================================
__global__ __launch_bounds__(256) void k4_attn(
    const float* __restrict__ bridge, const int* __restrict__ segid_ws,
    const int* __restrict__ imu_len,
    const float* __restrict__ Wqkv, const float* __restrict__ Wo,
    const float* __restrict__ ln1_g, const float* __restrict__ ln1_b,
    const float* __restrict__ Wf1, const float* __restrict__ bf1,
    const float* __restrict__ Wf2, const float* __restrict__ bf2,
    const float* __restrict__ ln2_g, const float* __restrict__ ln2_b,
    const float* __restrict__ Wout, const float* __restrict__ bout,
    float* __restrict__ tr_ws)
{
    const int b = blockIdx.x >> 3;
    const int chunk = blockIdx.x & 7;
    const int tid = threadIdx.x;
    __shared__ float kv[256][8];
    __shared__ int sid[256];
    __shared__ float part[32][8][8];
    {
        const int s2 = tid;
        const float4 h = *(const float4*)(bridge + (size_t)(s2 * 32 + b) * 4);
#pragma unroll
        for (int e = 0; e < 4; ++e) {
            kv[s2][e]     = h.x * Wqkv[16 + e] + h.y * Wqkv[20 + e] + h.z * Wqkv[24 + e] + h.w * Wqkv[28 + e];
            kv[s2][4 + e] = h.x * Wqkv[32 + e] + h.y * Wqkv[36 + e] + h.z * Wqkv[40 + e] + h.w * Wqkv[44 + e];
        }
        sid[s2] = segid_ws[b * 256 + s2];
    }
    __syncthreads();
    int last = (int)rintf((float)imu_len[b] * (1.0f / 256.0f));
    last = imin(imax(last, 2), 256);
    const int lq = tid & 31;
    const int jg = tid >> 5;
    const int sq = chunk * 32 + lq;
    {
        const float4 h = *(const float4*)(bridge + (size_t)(sq * 32 + b) * 4);
        float q[4];
#pragma unroll
        for (int e = 0; e < 4; ++e)
            q[e] = h.x * Wqkv[e] + h.y * Wqkv[4 + e] + h.z * Wqkv[8 + e] + h.w * Wqkv[12 + e];
        const bool vs = sq < last;
        const int ms = sid[sq];
        const float isq = 0.70710678118654752f;
        float m0 = -1e30f, l0 = 0.f, a00 = 0.f, a01 = 0.f;
        float m1 = -1e30f, l1 = 0.f, a10 = 0.f, a11 = 0.f;
#pragma unroll 4
        for (int jj = 0; jj < 32; ++jj) {
            const int j = jg * 32 + jj;
            const bool allowed = (j == sq) || (vs && (j < last) && (sid[j] == ms));
            const float sc0 = (q[0] * kv[j][0] + q[1] * kv[j][1]) * isq;
            const float sc1 = (q[2] * kv[j][2] + q[3] * kv[j][3]) * isq;
            {
                const float mn = allowed ? fmaxf(m0, sc0) : m0;
                const float c = __expf(m0 - mn);                      // arg <= 0 always
                const float e = allowed ? __expf(sc0 - mn) : 0.0f;    // select: no inf*0
                l0 = l0 * c + e; a00 = a00 * c + e * kv[j][4]; a01 = a01 * c + e * kv[j][5]; m0 = mn;
            }
            {
                const float mn = allowed ? fmaxf(m1, sc1) : m1;
                const float c = __expf(m1 - mn);
                const float e = allowed ? __expf(sc1 - mn) : 0.0f;
                l1 = l1 * c + e; a10 = a10 * c + e * kv[j][6]; a11 = a11 * c + e * kv[j][7]; m1 = mn;
            }
        }
        float* pp = part[lq][jg];
        pp[0] = m0; pp[1] = l0; pp[2] = a00; pp[3] = a01;
        pp[4] = m1; pp[5] = l1; pp[6] = a10; pp[7] = a11;
    }
    __syncthreads();
    if (tid < 32) {
        const int s = chunk * 32 + tid;
        float M0 = -1e30f, L0 = 0.f, A00 = 0.f, A01 = 0.f;
        float M1 = -1e30f, L1 = 0.f, A10 = 0.f, A11 = 0.f;
#pragma unroll
        for (int p = 0; p < 8; ++p) {
            const float* pp = part[tid][p];
            {
                const float mn = fmaxf(M0, pp[0]);
                const float c0 = __expf(M0 - mn), c1 = __expf(pp[0] - mn);   // args <= 0
                L0 = L0 * c0 + pp[1] * c1; A00 = A00 * c0 + pp[2] * c1; A01 = A01 * c0 + pp[3] * c1; M0 = mn;
            }
            {
                const float mn = fmaxf(M1, pp[4]);
                const float c0 = __expf(M1 - mn), c1 = __expf(pp[4] - mn);
                L1 = L1 * c0 + pp[5] * c1; A10 = A10 * c0 + pp[6] * c1; A11 = A11 * c0 + pp[7] * c1; M1 = mn;
            }
        }
        const float4 h = *(const float4*)(bridge + (size_t)(s * 32 + b) * 4);
        const float hb0 = h.x, hb1 = h.y, hb2 = h.z, hb3 = h.w;
        float ao[4] = {A00 / L0, A01 / L0, A10 / L1, A11 / L1};
        float x1[4];
#pragma unroll
        for (int jj = 0; jj < 4; ++jj)
            x1[jj] = ao[0] * Wo[jj] + ao[1] * Wo[4 + jj] + ao[2] * Wo[8 + jj] + ao[3] * Wo[12 + jj];
        x1[0] += hb0; x1[1] += hb1; x1[2] += hb2; x1[3] += hb3;
        float mean = 0.25f * (x1[0] + x1[1] + x1[2] + x1[3]);
        float var = 0.f;
#pragma unroll
        for (int i = 0; i < 4; ++i) { float d = x1[i] - mean; var += d * d; }
        var *= 0.25f;
        const float rs1 = rsqrtf(var + 1e-5f);
        float h1v[4];
#pragma unroll
        for (int i = 0; i < 4; ++i) h1v[i] = (x1[i] - mean) * rs1 * ln1_g[i] + ln1_b[i];
        float o2[4] = {bf2[0], bf2[1], bf2[2], bf2[3]};
#pragma unroll
        for (int kk = 0; kk < 16; ++kk) {
            float t = bf1[kk];
#pragma unroll
            for (int i = 0; i < 4; ++i) t = fmaf(h1v[i], Wf1[i * 16 + kk], t);
            t = fmaxf(t, 0.0f);
#pragma unroll
            for (int jj = 0; jj < 4; ++jj) o2[jj] = fmaf(t, Wf2[kk * 4 + jj], o2[jj]);
        }
        float x2[4];
#pragma unroll
        for (int i = 0; i < 4; ++i) x2[i] = h1v[i] + o2[i];
        float mean2 = 0.25f * (x2[0] + x2[1] + x2[2] + x2[3]);
        float var2 = 0.f;
#pragma unroll
        for (int i = 0; i < 4; ++i) { float d = x2[i] - mean2; var2 += d * d; }
        var2 *= 0.25f;
        const float rs2 = rsqrtf(var2 + 1e-5f);
        float h2v[4];
#pragma unroll
        for (int i = 0; i < 4; ++i) h2v[i] = (x2[i] - mean2) * rs2 * ln2_g[i] + ln2_b[i];
        float* tp = tr_ws + ((size_t)(b * 256 + s)) * 32;
#pragma unroll
        for (int mm = 0; mm < 32; ++mm)
            tp[mm] = bout[mm] + h2v[0] * Wout[mm] + h2v[1] * Wout[32 + mm]
                   + h2v[2] * Wout[64 + mm] + h2v[3] * Wout[96 + mm];
    }
}

// ============================================================================
// K5: atoms: atom_gen = (emb @ Wa + ba)*valid ; seg_interp gather from x
// grid (130, 32), 128 threads (120 active: d*20+i)
// ============================================================================
__global__ __launch_bounds__(128) void k5_atoms(
    const float* __restrict__ x, const float* __restrict__ tr_ws,
    const int* __restrict__ ends_ws, const int* __restrict__ starts_ws,
    const int* __restrict__ nk_ws,
    const float* __restrict__ Wa, const float* __restrict__ ba,
    float* __restrict__ out)
{
    const int a = blockIdx.x;
    const int b = blockIdx.y;
    const int tid = threadIdx.x;
    __shared__ float emb[32];
    const int e = ends_ws[b * 130 + a];
    const int st = starts_ws[b * 130 + a];
    const int nk = nk_ws[b];
    const float valid = (a <= nk) ? 1.0f : 0.0f;
    const int ec = imin(imax(e - 1, 0), 255);
    if (tid < 32) emb[tid] = tr_ws[((size_t)(b * 256 + ec)) * 32 + tid];
    __syncthreads();
    if (tid < 120) {
        float v = ba[tid];
#pragma unroll
        for (int f = 0; f < 32; ++f) v = fmaf(emb[f], Wa[f * 120 + tid], v);
        out[OFF_ATOM + ((size_t)(b * 130 + a)) * 120 + tid] = v * valid;
        const int d = tid / 20, i = tid % 20;
        const int ilen = (e - st) * 400;
        int idx = st * 400 + (i * ilen) / 20;
        idx = imin(imax(idx, 0), 102399);
        const int si = idx / 400, ti = idx % 400;
        const float px = x[(((size_t)b * 256 + si) * 6 + d) * 400 + ti];
        out[OFF_SEG + ((size_t)(b * 130 + a)) * 120 + tid] = px * valid;
    }
}

// ============================================================================
// K6: imu_gen GEMM: relu(bridge@Wd1+bd1) @ Wd2(64x2400) + bd2
// grid (256 n-tiles of 32, 10 m-tiles of 256), 256 threads, 8x4 micro-tile
// ============================================================================
__global__ __launch_bounds__(256) void k6_imu(
    const float* __restrict__ bridge, const float* __restrict__ Wd1,
    const float* __restrict__ bd1, const float* __restrict__ Wd2,
    const float* __restrict__ bd2, float* __restrict__ out)
{
    __shared__ float hl[64 * 32];     // [f][i]
    const int n0 = blockIdx.x * 32;
    const int mb = blockIdx.y;
    const int tid = threadIdx.x;
    for (int e = tid; e < 2048; e += 256) {
        const int f = e >> 5, i = e & 31;
        const float4 br = *(const float4*)(bridge + (size_t)(n0 + i) * 4);
        const float v = bd1[f] + br.x * Wd1[f] + br.y * Wd1[64 + f]
                      + br.z * Wd1[128 + f] + br.w * Wd1[192 + f];
        hl[f * 32 + i] = fmaxf(v, 0.0f);
    }
    __syncthreads();
    const int gm = tid & 63, gn = tid >> 6;
    const int m0 = mb * 256 + gm * 4;
    if (m0 >= 2400) return;
    float acc[8][4];
#pragma unroll
    for (int r = 0; r < 8; ++r)
#pragma unroll
        for (int c = 0; c < 4; ++c) acc[r][c] = 0.f;
#pragma unroll 4
    for (int f = 0; f < 64; ++f) {
        const float4 w4 = *(const float4*)&Wd2[(size_t)f * 2400 + m0];
        const float4 h0 = *(const float4*)&hl[f * 32 + gn * 8];
        const float4 h1 = *(const float4*)&hl[f * 32 + gn * 8 + 4];
        const float hv[8] = {h0.x, h0.y, h0.z, h0.w, h1.x, h1.y, h1.z, h1.w};
        const float wv[4] = {w4.x, w4.y, w4.z, w4.w};
#pragma unroll
        for (int r = 0; r < 8; ++r)
#pragma unroll
            for (int c = 0; c < 4; ++c) acc[r][c] = fmaf(hv[r], wv[c], acc[r][c]);
    }
    const float4 bb = *(const float4*)&bd2[m0];
#pragma unroll
    for (int r = 0; r < 8; ++r) {
        float4 o;
        o.x = acc[r][0] + bb.x; o.y = acc[r][1] + bb.y;
        o.z = acc[r][2] + bb.z; o.w = acc[r][3] + bb.w;
        *(float4*)&out[OFF_IMU + (size_t)(n0 + gn * 8 + r) * 2400 + m0] = o;
    }
}

// ============================================================================
extern "C" void kernel_launch(void* const* d_in, const int* in_sizes, int n_in,
                              void* d_out, int out_size, void* d_ws, size_t ws_size,
                              hipStream_t stream)
{
    const float* x        = (const float*)d_in[0];
    const float* imu_mask = (const float*)d_in[1];
    const int*   imu_len  = (const int*)  d_in[2];
    const float* conv_w   = (const float*)d_in[3];
    const float* conv_b   = (const float*)d_in[4];
    const float* W_b1     = (const float*)d_in[5];
    const float* b_b1     = (const float*)d_in[6];
    const float* W_fc     = (const float*)d_in[7];
    const float* b_fc     = (const float*)d_in[8];
    const float* Wqkv     = (const float*)d_in[9];
    const float* Wo       = (const float*)d_in[10];
    const float* ln1_g    = (const float*)d_in[11];
    const float* ln1_b    = (const float*)d_in[12];
    const float* Wf1      = (const float*)d_in[13];
    const float* bf1      = (const float*)d_in[14];
    const float* Wf2      = (const float*)d_in[15];
    const float* bf2      = (const float*)d_in[16];
    const float* ln2_g    = (const float*)d_in[17];
    const float* ln2_b    = (const float*)d_in[18];
    const float* Wout     = (const float*)d_in[19];
    const float* bout     = (const float*)d_in[20];
    const float* Wd1      = (const float*)d_in[21];
    const float* bd1      = (const float*)d_in[22];
    const float* Wd2      = (const float*)d_in[23];
    const float* bd2      = (const float*)d_in[24];
    const float* Wa       = (const float*)d_in[25];
    const float* ba       = (const float*)d_in[26];

    float* out = (float*)d_out;
    float* wsf = (float*)d_ws;
    int*   wsi = (int*)d_ws;

    float* bridge = wsf + WS_BRIDGE;
    float* tr_ws  = wsf + WS_TR;
    int* segid  = wsi + WS_SEGID;
    int* ends   = wsi + WS_ENDS;
    int* starts = wsi + WS_STARTS;
    int* nk     = wsi + WS_NK;

    k1_conv_bridge<<<2048, 256, 0, stream>>>(x, conv_w, conv_b, W_b1, b_b1, bridge);
    k23_forcast_seg<<<32, 256, 0, stream>>>(bridge, imu_mask, W_fc, b_fc, imu_len,
                                            out, segid, ends, starts, nk);
    k4_attn<<<256, 256, 0, stream>>>(bridge, segid, imu_len, Wqkv, Wo, ln1_g, ln1_b,
                                     Wf1, bf1, Wf2, bf2, ln2_g, ln2_b, Wout, bout, tr_ws);
    k5_atoms<<<dim3(130, 32), 128, 0, stream>>>(x, tr_ws, ends, starts, nk, Wa, ba, out);
    k6_imu<<<dim3(256, 10), 256, 0, stream>>>(bridge, Wd1, bd1, Wd2, bd2, out);
}

// Round 9
// 141.566 us; speedup vs baseline: 3.3833x; 3.3833x over previous
//
#include <hip/hip_runtime.h>
#include <math.h>

// ---- output layout ----
#define OFF_IMU  0
#define OFF_ATOM 19660800
#define OFF_SEG  20160000
#define OFF_FC   20659200
#define OFF_FL   20691968

// ---- ws layout (4-byte elements) ----
#define WS_BRIDGE 0        // 32768 floats  (8192 x 4)
#define WS_TR     32768    // 262144 floats (8192 x 32)
#define WS_SEGID  294912   // 8192 ints
#define WS_ENDS   303104   // 4160 ints
#define WS_STARTS 307264   // 4160 ints
#define WS_NK     311424   // 32 ints

static __device__ __forceinline__ int imin(int a, int b) { return a < b ? a : b; }
static __device__ __forceinline__ int imax(int a, int b) { return a > b ? a : b; }

// v_pk_fma_f32: S(.x,.y) += W(.x,.y) * broadcast(X.lo or X.hi)
#define PK_FMA_LO(S, W, X) \
    asm("v_pk_fma_f32 %0, %1, %2, %0 op_sel:[0,0,0] op_sel_hi:[1,0,1]" \
        : "+v"(S) : "v"(W), "v"(X))
#define PK_FMA_HI(S, W, X) \
    asm("v_pk_fma_f32 %0, %1, %2, %0 op_sel:[0,1,0] op_sel_hi:[1,1,1]" \
        : "+v"(S) : "v"(W), "v"(X))

union F4 { float4 q; float2 h[2]; };

// conv math for one 4-chunk at LDS address p (row stride 404 floats).
// Loads 6x (b128 + b64), 72 pk_fma. No persistent window state.
__device__ __forceinline__ void chunk_math(
    const float* p, const float2 (&W2)[18], const float2 cb2,
    float2& R0, float2& R1, float2& R2, float2& R3)
{
    float2 S0 = cb2, S1 = cb2, S2 = cb2, S3 = cb2;
#pragma unroll
    for (int ic = 0; ic < 6; ++ic) {
        const F4 a = *(const F4*)(p + ic * 404);
        const float2 n01 = *(const float2*)(p + ic * 404 + 4);
        const float2 c01 = a.h[0], c23 = a.h[1];
        const float2 w0 = W2[ic*3+0], w1 = W2[ic*3+1], w2 = W2[ic*3+2];
        PK_FMA_LO(S0, w0, c01); PK_FMA_HI(S0, w1, c01); PK_FMA_LO(S0, w2, c23);
        PK_FMA_HI(S1, w0, c01); PK_FMA_LO(S1, w1, c23); PK_FMA_HI(S1, w2, c23);
        PK_FMA_LO(S2, w0, c23); PK_FMA_HI(S2, w1, c23); PK_FMA_LO(S2, w2, n01);
        PK_FMA_HI(S3, w0, c23); PK_FMA_LO(S3, w1, n01); PK_FMA_HI(S3, w2, n01);
    }
    R0 = S0; R1 = S1; R2 = S2; R3 = S3;
}

// ============================================================================
// K1: conv1d(6->32,k=3,VALID) + ReLU + half-mean-pool + bridge sigmoid MLP
// 2048 blocks x 512 threads; 4 samples/block, 8 waves = (sample, half).
// Lane l: oc-pair pr=l&15, stride-slot q=l>>4. Lane computes chunks q+4i
// (i=0..11) of its half; q<2 lanes handle tail chunks 48,49. The staged
// sample bytes are shared by 2 waves -> 2x resident waves vs round 7.
// Cross-half t=199 fixup routed via LDS (extraL) + barrier.
// ============================================================================
__global__ __launch_bounds__(512) void k1_conv_bridge(
    const float* __restrict__ x, const float* __restrict__ conv_w,
    const float* __restrict__ conv_b, const float* __restrict__ W_b1,
    const float* __restrict__ b_b1, float* __restrict__ bridge)
{
    __shared__ __align__(16) float xs[4][2424];  // [smp][ic*404 + t]; 400..403 zeroed
    __shared__ float pooledL[4][64];
    __shared__ float2 extraL[4][16];
    const int tid = threadIdx.x;
    const int n0 = blockIdx.x * 4;

    const int wv8 = tid >> 6;          // wave 0..7
    const int smp = wv8 >> 1;          // sample
    const int hg  = wv8 & 1;           // pooling half
    const int l   = tid & 63;
    const int pr  = l & 15;            // oc pair: 2pr, 2pr+1
    const int q   = l >> 4;            // chunk stride slot 0..3

    // weight pairs (loop-invariant): W2[j] = (w[2pr][j], w[2pr+1][j])
    float2 W2[18];
    {
        const float* wa = conv_w + (2 * pr) * 18;
        const float* wb = wa + 18;
#pragma unroll
        for (int j = 0; j < 18; ++j) W2[j] = make_float2(wa[j], wb[j]);
    }
    const float2 cb2 = make_float2(conv_b[2 * pr], conv_b[2 * pr + 1]);

    // stage 4 samples of x into LDS (coalesced float4)
    const float* xn = x + (size_t)n0 * 2400;
    for (int i = tid; i < 2400; i += 512) {
        const float4 v = ((const float4*)xn)[i];
        const int s2 = i / 600;
        const int r = i - s2 * 600;
        const int ic = r / 100, t4 = (r - ic * 100) * 4;
        *(float4*)&xs[s2][ic * 404 + t4] = v;
    }
    if (tid < 96) {                    // zero pads so tail multiplies stay finite
        const int s2 = tid / 24, r = tid - s2 * 24;
        xs[s2][(r >> 2) * 404 + 400 + (r & 3)] = 0.0f;
    }
    __syncthreads();

    const float* rb = &xs[smp][hg * 200 + q * 4];   // lane base; offsets imm
    float2 accM = make_float2(0.0f, 0.0f);
    float2 extra = make_float2(0.0f, 0.0f);

    // 12 interior chunks c = q + 4i  (c <= 47: always fully valid)
#pragma unroll
    for (int i = 0; i < 12; ++i) {
        float2 R0, R1, R2, R3;
        chunk_math(rb + i * 16, W2, cb2, R0, R1, R2, R3);
        accM.x += fmaxf(R0.x,0.f)+fmaxf(R1.x,0.f)+fmaxf(R2.x,0.f)+fmaxf(R3.x,0.f);
        accM.y += fmaxf(R0.y,0.f)+fmaxf(R1.y,0.f)+fmaxf(R2.y,0.f)+fmaxf(R3.y,0.f);
    }

    // tail: chunk 48 (q==0 lanes), chunk 49 (q==1 lanes)
    if (q < 2) {
        float2 R0, R1, R2, R3;
        chunk_math(rb + 192, W2, cb2, R0, R1, R2, R3);   // c = q + 48
        const float r0x = fmaxf(R0.x,0.f), r0y = fmaxf(R0.y,0.f);
        const float r1x = fmaxf(R1.x,0.f), r1y = fmaxf(R1.y,0.f);
        const float r2x = fmaxf(R2.x,0.f), r2y = fmaxf(R2.y,0.f);
        const float r3x = fmaxf(R3.x,0.f), r3y = fmaxf(R3.y,0.f);
        if (q == 0) {                  // c=48: t interior, all valid
            accM.x += r0x + r1x + r2x + r3x;
            accM.y += r0y + r1y + r2y + r3y;
        } else if (hg == 0) {          // c=49, half0: t=196..198 + extra t=199
            accM.x += r0x + r1x + r2x;  extra.x = r3x;
            accM.y += r0y + r1y + r2y;  extra.y = r3y;
        } else {                       // c=49, half1: t=396,397 valid only
            accM.x += r0x + r1x;
            accM.y += r0y + r1y;
        }
    }

    // reduce over q slots (l = pr + 16q): butterfly 16 then 32
    accM.x += __shfl_xor(accM.x, 16); accM.x += __shfl_xor(accM.x, 32);
    accM.y += __shfl_xor(accM.y, 16); accM.y += __shfl_xor(accM.y, 32);
    extra.x += __shfl_xor(extra.x, 16); extra.x += __shfl_xor(extra.x, 32);
    extra.y += __shfl_xor(extra.y, 16); extra.y += __shfl_xor(extra.y, 32);

    const float inv199 = 1.0f / 199.0f;
    if (hg == 0 && l < 16) {           // half0 writes + export extra(t=199)
        pooledL[smp][(2 * pr + 0) * 2 + 0] = accM.x * inv199;
        pooledL[smp][(2 * pr + 1) * 2 + 0] = accM.y * inv199;
        extraL[smp][pr] = extra;
    }
    __syncthreads();
    if (hg == 1 && l < 16) {           // half1 = own sum + t=199 from half0 wave
        const float2 ex = extraL[smp][pr];
        pooledL[smp][(2 * pr + 0) * 2 + 1] = (accM.x + ex.x) * inv199;
        pooledL[smp][(2 * pr + 1) * 2 + 1] = (accM.y + ex.y) * inv199;
    }
    __syncthreads();

    // bridge MLP: first 256 threads; sample = tid>>6, feature f = tid&63
    if (tid < 256) {
        const int s2 = tid >> 6, f = tid & 63;
        const float v = pooledL[s2][f];
        const float4 wb = *(const float4*)(W_b1 + f * 4);
        float p0 = v * wb.x, p1 = v * wb.y, p2 = v * wb.z, p3 = v * wb.w;
#pragma unroll
        for (int off = 1; off < 64; off <<= 1) {
            p0 += __shfl_xor(p0, off, 64);
            p1 += __shfl_xor(p1, off, 64);
            p2 += __shfl_xor(p2, off, 64);
            p3 += __shfl_xor(p3, off, 64);
        }
        if (f == 0) {
            float* bp = bridge + (size_t)(n0 + s2) * 4;
            bp[0] = 1.0f / (1.0f + __expf(-(p0 + b_b1[0])));
            bp[1] = 1.0f / (1.0f + __expf(-(p1 + b_b1[1])));
            bp[2] = 1.0f / (1.0f + __expf(-(p2 + b_b1[2])));
            bp[3] = 1.0f / (1.0f + __expf(-(p3 + b_b1[3])));
        }
    }
}

// ============================================================================
// K23: forcast + masked floss (to d_out) fused with per-batch segmentation.
// one block per b (32 x 256)
// ============================================================================
__global__ __launch_bounds__(256) void k23_forcast_seg(
    const float* __restrict__ bridge, const float* __restrict__ imu_mask,
    const float* __restrict__ W_fc, const float* __restrict__ b_fc,
    const int* __restrict__ imu_len, float* __restrict__ out,
    int* __restrict__ segid_ws, int* __restrict__ ends_ws,
    int* __restrict__ starts_ws, int* __restrict__ nk_ws)
{
    const int b = blockIdx.x, tid = threadIdx.x;
    const int n = b * 256 + tid;
    __shared__ float fl[256];
    __shared__ float sel[256];
    __shared__ float sp[256];
    __shared__ int pk[256];
    __shared__ int sc[2][256];
    __shared__ int kpl[256];

    // ---- forcast + floss ----
    float sh[4], cur[4];
#pragma unroll
    for (int j = 0; j < 4; ++j) {
        sh[j] = (tid == 0) ? 0.0f : bridge[(n - 1) * 4 + j];
        cur[j] = bridge[n * 4 + j];
    }
    const float fm = ((tid == 0) ? 0.0f : 1.0f) * imu_mask[n];
    float flv = 0.0f;
#pragma unroll
    for (int j = 0; j < 4; ++j) {
        float f = b_fc[j];
#pragma unroll
        for (int i = 0; i < 4; ++i) f = fmaf(sh[i], W_fc[i * 4 + j], f);
        out[OFF_FC + n * 4 + j] = f;
        const float d = (f - cur[j]) * fm;
        flv = fmaf(d, d, flv);
    }
    flv *= 0.25f;
    const bool lm = (tid >= 2) && (tid < 254);
    flv = (flv > 0.001f && lm) ? flv : 0.0f;
    out[OFF_FL + n] = flv;

    // ---- segmentation ----
    fl[tid] = flv;
    sp[tid] = 0.0f;
    __syncthreads();
    if (tid < 64) {                       // sel: windows of 4, first-max
        const int base = tid * 4;
        float m = fl[base]; int idx = 0;
#pragma unroll
        for (int i = 1; i < 4; ++i) { float v = fl[base + i]; if (v > m) { m = v; idx = i; } }
#pragma unroll
        for (int i = 0; i < 4; ++i) sel[base + i] = (i == idx) ? m : 0.0f;
    }
    __syncthreads();
    if (tid < 63) {                       // sel2 on sel[2:254), 63 windows of 4
        const int base = 2 + tid * 4;
        float m = sel[base]; int idx = 0;
#pragma unroll
        for (int i = 1; i < 4; ++i) { float v = sel[base + i]; if (v > m) { m = v; idx = i; } }
        sp[base + idx] = (m > 0.0f) ? 1.0f : 0.0f;
    }
    __syncthreads();
    int last = (int)rintf((float)imu_len[b] * (1.0f / 256.0f));  // half-even
    last = imin(imax(last, 2), 256);
    const int point = ((sp[tid] > 0.0f) && (tid < last)) ? 1 : 0;
    pk[tid] = point;
    __syncthreads();
    const int pnext = (tid < 255) ? pk[tid + 1] : 0;
    const int bnd = pnext | ((tid + 1 == last) ? 1 : 0);
    const int kept = (point && !bnd) ? 1 : 0;
    __syncthreads();
    sc[0][tid] = kept;
    __syncthreads();
    int src = 0;                          // Hillis-Steele inclusive scan
    for (int off = 1; off < 256; off <<= 1) {
        const int v = sc[src][tid] + ((tid >= off) ? sc[src][tid - off] : 0);
        sc[src ^ 1][tid] = v;
        __syncthreads();
        src ^= 1;
    }
    const int myid = sc[src][tid];
    segid_ws[b * 256 + tid] = myid;
    const int nk = sc[src][255];
    if (kept) kpl[myid - 1] = tid;
    __syncthreads();
    if (tid < 130) {
        ends_ws[b * 130 + tid] = (tid < nk) ? kpl[tid] : last;
        starts_ws[b * 130 + tid] = (tid == 0) ? 0 : ((tid - 1 < nk) ? kpl[tid - 1] : last);
    }
    if (tid == 0) nk_ws[b] = nk;
}

// ============================================================================
// K4: segment-masked attention (DM=4, 2 heads) + transformer block + tr_out
// grid 256 = (b, 32-query chunk), 256 threads: 8 j-groups x 32 queries,
// LDS online-softmax merge. NOTE hb[b,s] = bridge[s*32 + b] (scrambled).
// exp() only evaluated with argument <= 0 (select, never mask-multiply).
// ============================================================================
__global__ __launch_bounds__(256) void k4_attn(
    const float* __restrict__ bridge, const int* __restrict__ segid_ws,
    const int* __restrict__ imu_len,
    const float* __restrict__ Wqkv, const float* __restrict__ Wo,
    const float* __restrict__ ln1_g, const float* __restrict__ ln1_b,
    const float* __restrict__ Wf1, const float* __restrict__ bf1,
    const float* __restrict__ Wf2, const float* __restrict__ bf2,
    const float* __restrict__ ln2_g, const float* __restrict__ ln2_b,
    const float* __restrict__ Wout, const float* __restrict__ bout,
    float* __restrict__ tr_ws)
{
    const int b = blockIdx.x >> 3;
    const int chunk = blockIdx.x & 7;
    const int tid = threadIdx.x;
    __shared__ float kv[256][8];
    __shared__ int sid[256];
    __shared__ float part[32][8][8];
    {
        const int s2 = tid;
        const float4 h = *(const float4*)(bridge + (size_t)(s2 * 32 + b) * 4);
#pragma unroll
        for (int e = 0; e < 4; ++e) {
            kv[s2][e]     = h.x * Wqkv[16 + e] + h.y * Wqkv[20 + e] + h.z * Wqkv[24 + e] + h.w * Wqkv[28 + e];
            kv[s2][4 + e] = h.x * Wqkv[32 + e] + h.y * Wqkv[36 + e] + h.z * Wqkv[40 + e] + h.w * Wqkv[44 + e];
        }
        sid[s2] = segid_ws[b * 256 + s2];
    }
    __syncthreads();
    int last = (int)rintf((float)imu_len[b] * (1.0f / 256.0f));
    last = imin(imax(last, 2), 256);
    const int lq = tid & 31;
    const int jg = tid >> 5;
    const int sq = chunk * 32 + lq;
    {
        const float4 h = *(const float4*)(bridge + (size_t)(sq * 32 + b) * 4);
        float q[4];
#pragma unroll
        for (int e = 0; e < 4; ++e)
            q[e] = h.x * Wqkv[e] + h.y * Wqkv[4 + e] + h.z * Wqkv[8 + e] + h.w * Wqkv[12 + e];
        const bool vs = sq < last;
        const int ms = sid[sq];
        const float isq = 0.70710678118654752f;
        float m0 = -1e30f, l0 = 0.f, a00 = 0.f, a01 = 0.f;
        float m1 = -1e30f, l1 = 0.f, a10 = 0.f, a11 = 0.f;
#pragma unroll 4
        for (int jj = 0; jj < 32; ++jj) {
            const int j = jg * 32 + jj;
            const bool allowed = (j == sq) || (vs && (j < last) && (sid[j] == ms));
            const float sc0 = (q[0] * kv[j][0] + q[1] * kv[j][1]) * isq;
            const float sc1 = (q[2] * kv[j][2] + q[3] * kv[j][3]) * isq;
            {
                const float mn = allowed ? fmaxf(m0, sc0) : m0;
                const float c = __expf(m0 - mn);                      // arg <= 0 always
                const float e = allowed ? __expf(sc0 - mn) : 0.0f;    // select: no inf*0
                l0 = l0 * c + e; a00 = a00 * c + e * kv[j][4]; a01 = a01 * c + e * kv[j][5]; m0 = mn;
            }
            {
                const float mn = allowed ? fmaxf(m1, sc1) : m1;
                const float c = __expf(m1 - mn);
                const float e = allowed ? __expf(sc1 - mn) : 0.0f;
                l1 = l1 * c + e; a10 = a10 * c + e * kv[j][6]; a11 = a11 * c + e * kv[j][7]; m1 = mn;
            }
        }
        float* pp = part[lq][jg];
        pp[0] = m0; pp[1] = l0; pp[2] = a00; pp[3] = a01;
        pp[4] = m1; pp[5] = l1; pp[6] = a10; pp[7] = a11;
    }
    __syncthreads();
    if (tid < 32) {
        const int s = chunk * 32 + tid;
        float M0 = -1e30f, L0 = 0.f, A00 = 0.f, A01 = 0.f;
        float M1 = -1e30f, L1 = 0.f, A10 = 0.f, A11 = 0.f;
#pragma unroll
        for (int p = 0; p < 8; ++p) {
            const float* pp = part[tid][p];
            {
                const float mn = fmaxf(M0, pp[0]);
                const float c0 = __expf(M0 - mn), c1 = __expf(pp[0] - mn);   // args <= 0
                L0 = L0 * c0 + pp[1] * c1; A00 = A00 * c0 + pp[2] * c1; A01 = A01 * c0 + pp[3] * c1; M0 = mn;
            }
            {
                const float mn = fmaxf(M1, pp[4]);
                const float c0 = __expf(M1 - mn), c1 = __expf(pp[4] - mn);
                L1 = L1 * c0 + pp[5] * c1; A10 = A10 * c0 + pp[6] * c1; A11 = A11 * c0 + pp[7] * c1; M1 = mn;
            }
        }
        const float4 h = *(const float4*)(bridge + (size_t)(s * 32 + b) * 4);
        const float hb0 = h.x, hb1 = h.y, hb2 = h.z, hb3 = h.w;
        float ao[4] = {A00 / L0, A01 / L0, A10 / L1, A11 / L1};
        float x1[4];
#pragma unroll
        for (int jj = 0; jj < 4; ++jj)
            x1[jj] = ao[0] * Wo[jj] + ao[1] * Wo[4 + jj] + ao[2] * Wo[8 + jj] + ao[3] * Wo[12 + jj];
        x1[0] += hb0; x1[1] += hb1; x1[2] += hb2; x1[3] += hb3;
        float mean = 0.25f * (x1[0] + x1[1] + x1[2] + x1[3]);
        float var = 0.f;
#pragma unroll
        for (int i = 0; i < 4; ++i) { float d = x1[i] - mean; var += d * d; }
        var *= 0.25f;
        const float rs1 = rsqrtf(var + 1e-5f);
        float h1v[4];
#pragma unroll
        for (int i = 0; i < 4; ++i) h1v[i] = (x1[i] - mean) * rs1 * ln1_g[i] + ln1_b[i];
        float o2[4] = {bf2[0], bf2[1], bf2[2], bf2[3]};
#pragma unroll
        for (int kk = 0; kk < 16; ++kk) {
            float t = bf1[kk];
#pragma unroll
            for (int i = 0; i < 4; ++i) t = fmaf(h1v[i], Wf1[i * 16 + kk], t);
            t = fmaxf(t, 0.0f);
#pragma unroll
            for (int jj = 0; jj < 4; ++jj) o2[jj] = fmaf(t, Wf2[kk * 4 + jj], o2[jj]);
        }
        float x2[4];
#pragma unroll
        for (int i = 0; i < 4; ++i) x2[i] = h1v[i] + o2[i];
        float mean2 = 0.25f * (x2[0] + x2[1] + x2[2] + x2[3]);
        float var2 = 0.f;
#pragma unroll
        for (int i = 0; i < 4; ++i) { float d = x2[i] - mean2; var2 += d * d; }
        var2 *= 0.25f;
        const float rs2 = rsqrtf(var2 + 1e-5f);
        float h2v[4];
#pragma unroll
        for (int i = 0; i < 4; ++i) h2v[i] = (x2[i] - mean2) * rs2 * ln2_g[i] + ln2_b[i];
        float* tp = tr_ws + ((size_t)(b * 256 + s)) * 32;
#pragma unroll
        for (int mm = 0; mm < 32; ++mm)
            tp[mm] = bout[mm] + h2v[0] * Wout[mm] + h2v[1] * Wout[32 + mm]
                   + h2v[2] * Wout[64 + mm] + h2v[3] * Wout[96 + mm];
    }
}

// ============================================================================
// K5: atoms: atom_gen = (emb @ Wa + ba)*valid ; seg_interp gather from x
// grid (130, 32), 128 threads (120 active: d*20+i)
// ============================================================================
__global__ __launch_bounds__(128) void k5_atoms(
    const float* __restrict__ x, const float* __restrict__ tr_ws,
    const int* __restrict__ ends_ws, const int* __restrict__ starts_ws,
    const int* __restrict__ nk_ws,
    const float* __restrict__ Wa, const float* __restrict__ ba,
    float* __restrict__ out)
{
    const int a = blockIdx.x;
    const int b = blockIdx.y;
    const int tid = threadIdx.x;
    __shared__ float emb[32];
    const int e = ends_ws[b * 130 + a];
    const int st = starts_ws[b * 130 + a];
    const int nk = nk_ws[b];
    const float valid = (a <= nk) ? 1.0f : 0.0f;
    const int ec = imin(imax(e - 1, 0), 255);
    if (tid < 32) emb[tid] = tr_ws[((size_t)(b * 256 + ec)) * 32 + tid];
    __syncthreads();
    if (tid < 120) {
        float v = ba[tid];
#pragma unroll
        for (int f = 0; f < 32; ++f) v = fmaf(emb[f], Wa[f * 120 + tid], v);
        out[OFF_ATOM + ((size_t)(b * 130 + a)) * 120 + tid] = v * valid;
        const int d = tid / 20, i = tid % 20;
        const int ilen = (e - st) * 400;
        int idx = st * 400 + (i * ilen) / 20;
        idx = imin(imax(idx, 0), 102399);
        const int si = idx / 400, ti = idx % 400;
        const float px = x[(((size_t)b * 256 + si) * 6 + d) * 400 + ti];
        out[OFF_SEG + ((size_t)(b * 130 + a)) * 120 + tid] = px * valid;
    }
}

// ============================================================================
// K6: imu_gen GEMM: relu(bridge@Wd1+bd1) @ Wd2(64x2400) + bd2
// grid (256 n-tiles of 32, 10 m-tiles of 256), 256 threads, 8x4 micro-tile
// ============================================================================
__global__ __launch_bounds__(256) void k6_imu(
    const float* __restrict__ bridge, const float* __restrict__ Wd1,
    const float* __restrict__ bd1, const float* __restrict__ Wd2,
    const float* __restrict__ bd2, float* __restrict__ out)
{
    __shared__ float hl[64 * 32];     // [f][i]
    const int n0 = blockIdx.x * 32;
    const int mb = blockIdx.y;
    const int tid = threadIdx.x;
    for (int e = tid; e < 2048; e += 256) {
        const int f = e >> 5, i = e & 31;
        const float4 br = *(const float4*)(bridge + (size_t)(n0 + i) * 4);
        const float v = bd1[f] + br.x * Wd1[f] + br.y * Wd1[64 + f]
                      + br.z * Wd1[128 + f] + br.w * Wd1[192 + f];
        hl[f * 32 + i] = fmaxf(v, 0.0f);
    }
    __syncthreads();
    const int gm = tid & 63, gn = tid >> 6;
    const int m0 = mb * 256 + gm * 4;
    if (m0 >= 2400) return;
    float acc[8][4];
#pragma unroll
    for (int r = 0; r < 8; ++r)
#pragma unroll
        for (int c = 0; c < 4; ++c) acc[r][c] = 0.f;
#pragma unroll 4
    for (int f = 0; f < 64; ++f) {
        const float4 w4 = *(const float4*)&Wd2[(size_t)f * 2400 + m0];
        const float4 h0 = *(const float4*)&hl[f * 32 + gn * 8];
        const float4 h1 = *(const float4*)&hl[f * 32 + gn * 8 + 4];
        const float hv[8] = {h0.x, h0.y, h0.z, h0.w, h1.x, h1.y, h1.z, h1.w};
        const float wv[4] = {w4.x, w4.y, w4.z, w4.w};
#pragma unroll
        for (int r = 0; r < 8; ++r)
#pragma unroll
            for (int c = 0; c < 4; ++c) acc[r][c] = fmaf(hv[r], wv[c], acc[r][c]);
    }
    const float4 bb = *(const float4*)&bd2[m0];
#pragma unroll
    for (int r = 0; r < 8; ++r) {
        float4 o;
        o.x = acc[r][0] + bb.x; o.y = acc[r][1] + bb.y;
        o.z = acc[r][2] + bb.z; o.w = acc[r][3] + bb.w;
        *(float4*)&out[OFF_IMU + (size_t)(n0 + gn * 8 + r) * 2400 + m0] = o;
    }
}

// ============================================================================
extern "C" void kernel_launch(void* const* d_in, const int* in_sizes, int n_in,
                              void* d_out, int out_size, void* d_ws, size_t ws_size,
                              hipStream_t stream)
{
    const float* x        = (const float*)d_in[0];
    const float* imu_mask = (const float*)d_in[1];
    const int*   imu_len  = (const int*)  d_in[2];
    const float* conv_w   = (const float*)d_in[3];
    const float* conv_b   = (const float*)d_in[4];
    const float* W_b1     = (const float*)d_in[5];
    const float* b_b1     = (const float*)d_in[6];
    const float* W_fc     = (const float*)d_in[7];
    const float* b_fc     = (const float*)d_in[8];
    const float* Wqkv     = (const float*)d_in[9];
    const float* Wo       = (const float*)d_in[10];
    const float* ln1_g    = (const float*)d_in[11];
    const float* ln1_b    = (const float*)d_in[12];
    const float* Wf1      = (const float*)d_in[13];
    const float* bf1      = (const float*)d_in[14];
    const float* Wf2      = (const float*)d_in[15];
    const float* bf2      = (const float*)d_in[16];
    const float* ln2_g    = (const float*)d_in[17];
    const float* ln2_b    = (const float*)d_in[18];
    const float* Wout     = (const float*)d_in[19];
    const float* bout     = (const float*)d_in[20];
    const float* Wd1      = (const float*)d_in[21];
    const float* bd1      = (const float*)d_in[22];
    const float* Wd2      = (const float*)d_in[23];
    const float* bd2      = (const float*)d_in[24];
    const float* Wa       = (const float*)d_in[25];
    const float* ba       = (const float*)d_in[26];

    float* out = (float*)d_out;
    float* wsf = (float*)d_ws;
    int*   wsi = (int*)d_ws;

    float* bridge = wsf + WS_BRIDGE;
    float* tr_ws  = wsf + WS_TR;
    int* segid  = wsi + WS_SEGID;
    int* ends   = wsi + WS_ENDS;
    int* starts = wsi + WS_STARTS;
    int* nk     = wsi + WS_NK;

    k1_conv_bridge<<<2048, 512, 0, stream>>>(x, conv_w, conv_b, W_b1, b_b1, bridge);
    k23_forcast_seg<<<32, 256, 0, stream>>>(bridge, imu_mask, W_fc, b_fc, imu_len,
                                            out, segid, ends, starts, nk);
    k4_attn<<<256, 256, 0, stream>>>(bridge, segid, imu_len, Wqkv, Wo, ln1_g, ln1_b,
                                     Wf1, bf1, Wf2, bf2, ln2_g, ln2_b, Wout, bout, tr_ws);
    k5_atoms<<<dim3(130, 32), 128, 0, stream>>>(x, tr_ws, ends, starts, nk, Wa, ba, out);
    k6_imu<<<dim3(256, 10), 256, 0, stream>>>(bridge, Wd1, bd1, Wd2, bd2, out);
}

// Round 10
// 115.831 us; speedup vs baseline: 4.1350x; 1.2222x over previous
//
#include <hip/hip_runtime.h>
#include <math.h>

// ---- output layout ----
#define OFF_IMU  0
#define OFF_ATOM 19660800
#define OFF_SEG  20160000
#define OFF_FC   20659200
#define OFF_FL   20691968

// ---- ws layout (4-byte elements) ----
#define WS_BRIDGE 0        // 32768 floats  (8192 x 4)
#define WS_TR     32768    // 262144 floats (8192 x 32)
#define WS_ENDS   303104   // 4160 ints
#define WS_STARTS 307264   // 4160 ints
#define WS_NK     311424   // 32 ints

static __device__ __forceinline__ int imin(int a, int b) { return a < b ? a : b; }
static __device__ __forceinline__ int imax(int a, int b) { return a > b ? a : b; }

// v_pk_fma_f32: S(.x,.y) += W(.x,.y) * broadcast(X.lo or X.hi)
#define PK_FMA_LO(S, W, X) \
    asm("v_pk_fma_f32 %0, %1, %2, %0 op_sel:[0,0,0] op_sel_hi:[1,0,1]" \
        : "+v"(S) : "v"(W), "v"(X))
#define PK_FMA_HI(S, W, X) \
    asm("v_pk_fma_f32 %0, %1, %2, %0 op_sel:[0,1,0] op_sel_hi:[1,1,1]" \
        : "+v"(S) : "v"(W), "v"(X))

union F4 { float4 q; float2 h[2]; };

// ============================================================================
// K1 (round-6 best, 66.8us measured): conv1d + ReLU + half-mean-pool + bridge.
// 2048 blocks x 256 threads; 4 samples/block, one WAVE per sample.
// Lane l: oc-pair pr=l&15, half hg=(l>>4)&1, quarter q=l>>5; packed fp32 math,
// rolling window (4 groups x 6 chunks), imm-offset ds_read_b128 only.
// ============================================================================
__global__ __launch_bounds__(256) void k1_conv_bridge(
    const float* __restrict__ x, const float* __restrict__ conv_w,
    const float* __restrict__ conv_b, const float* __restrict__ W_b1,
    const float* __restrict__ b_b1, float* __restrict__ bridge)
{
    __shared__ __align__(16) float xs[4][2424];  // [smp][ic*404 + t]; 400..403 zeroed
    __shared__ float pooledL[4][64];
    const int tid = threadIdx.x;
    const int n0 = blockIdx.x * 4;

    const int wv = tid >> 6;           // wave = sample
    const int l  = tid & 63;
    const int pr = l & 15;             // oc pair: 2pr, 2pr+1
    const int hg = (l >> 4) & 1;       // pooling half
    const int q  = l >> 5;             // quarter within half

    float2 W2[18];
    {
        const float* wa = conv_w + (2 * pr) * 18;
        const float* wb = wa + 18;
#pragma unroll
        for (int j = 0; j < 18; ++j) W2[j] = make_float2(wa[j], wb[j]);
    }
    const float2 cb2 = make_float2(conv_b[2 * pr], conv_b[2 * pr + 1]);

    const float* xn = x + (size_t)n0 * 2400;
    for (int i = tid; i < 2400; i += 256) {
        const float4 v = ((const float4*)xn)[i];
        const int smp = i / 600;
        const int r = i - smp * 600;
        const int ic = r / 100, t4 = (r - ic * 100) * 4;
        *(float4*)&xs[smp][ic * 404 + t4] = v;
    }
    if (tid < 96) {                    // zero pads so tail multiplies stay finite
        const int smp = tid / 24, r = tid - smp * 24;
        xs[smp][(r >> 2) * 404 + 400 + (r & 3)] = 0.0f;
    }
    __syncthreads();

    const float* rb = &xs[wv][hg * 200 + q * 100];
    float2 accMain = make_float2(0.0f, 0.0f);
    float2 extra   = make_float2(0.0f, 0.0f);

    float2 c01[6], c23[6];             // rolling window pairs
#pragma unroll
    for (int ic = 0; ic < 6; ++ic) {
        const F4 f = *(const F4*)(rb + ic * 404);
        c01[ic] = f.h[0]; c23[ic] = f.h[1];
    }

    for (int g = 0; g < 4; ++g) {
#pragma unroll
        for (int u = 0; u < 6; ++u) {
            float2 S0 = cb2, S1 = cb2, S2 = cb2, S3 = cb2;
#pragma unroll
            for (int ic = 0; ic < 6; ++ic) {
                const F4 nf = *(const F4*)(rb + ic * 404 + (u + 1) * 4);
                const float2 n01 = nf.h[0];
                const float2 w0 = W2[ic*3+0], w1 = W2[ic*3+1], w2 = W2[ic*3+2];
                PK_FMA_LO(S0, w0, c01[ic]); PK_FMA_HI(S0, w1, c01[ic]); PK_FMA_LO(S0, w2, c23[ic]);
                PK_FMA_HI(S1, w0, c01[ic]); PK_FMA_LO(S1, w1, c23[ic]); PK_FMA_HI(S1, w2, c23[ic]);
                PK_FMA_LO(S2, w0, c23[ic]); PK_FMA_HI(S2, w1, c23[ic]); PK_FMA_LO(S2, w2, n01);
                PK_FMA_HI(S3, w0, c23[ic]); PK_FMA_LO(S3, w1, n01);     PK_FMA_HI(S3, w2, n01);
                c01[ic] = n01; c23[ic] = nf.h[1];
            }
            accMain.x += fmaxf(S0.x,0.f)+fmaxf(S1.x,0.f)+fmaxf(S2.x,0.f)+fmaxf(S3.x,0.f);
            accMain.y += fmaxf(S0.y,0.f)+fmaxf(S1.y,0.f)+fmaxf(S2.y,0.f)+fmaxf(S3.y,0.f);
        }
        rb += 24;
    }

    // tail chunk 24 (t = qbase+96..99)
    {
        float2 S0 = cb2, S1 = cb2, S2 = cb2, S3 = cb2;
#pragma unroll
        for (int ic = 0; ic < 6; ++ic) {
            const F4 nf = *(const F4*)(rb + ic * 404 + 4);
            const float2 n01 = nf.h[0];
            const float2 w0 = W2[ic*3+0], w1 = W2[ic*3+1], w2 = W2[ic*3+2];
            PK_FMA_LO(S0, w0, c01[ic]); PK_FMA_HI(S0, w1, c01[ic]); PK_FMA_LO(S0, w2, c23[ic]);
            PK_FMA_HI(S1, w0, c01[ic]); PK_FMA_LO(S1, w1, c23[ic]); PK_FMA_HI(S1, w2, c23[ic]);
            PK_FMA_LO(S2, w0, c23[ic]); PK_FMA_HI(S2, w1, c23[ic]); PK_FMA_LO(S2, w2, n01);
            PK_FMA_HI(S3, w0, c23[ic]); PK_FMA_LO(S3, w1, n01);     PK_FMA_HI(S3, w2, n01);
        }
        const float r0x = fmaxf(S0.x,0.f), r0y = fmaxf(S0.y,0.f);
        const float r1x = fmaxf(S1.x,0.f), r1y = fmaxf(S1.y,0.f);
        const float r2x = fmaxf(S2.x,0.f), r2y = fmaxf(S2.y,0.f);
        const float r3x = fmaxf(S3.x,0.f), r3y = fmaxf(S3.y,0.f);
        if (q == 0) {
            accMain.x += r0x + r1x + r2x + r3x;
            accMain.y += r0y + r1y + r2y + r3y;
        } else if (hg == 0) {
            accMain.x += r0x + r1x + r2x;  extra.x = r3x;
            accMain.y += r0y + r1y + r2y;  extra.y = r3y;
        } else {
            accMain.x += r0x + r1x;
            accMain.y += r0y + r1y;
        }
    }

    float2 tot;
    tot.x = accMain.x + __shfl_xor(accMain.x, 32);
    tot.y = accMain.y + __shfl_xor(accMain.y, 32);
    const float exx = __shfl_xor(extra.x, 16);
    const float exy = __shfl_xor(extra.y, 16);
    if (hg) { tot.x += exx; tot.y += exy; }
    if (q) {
        pooledL[wv][(2 * pr + 0) * 2 + hg] = tot.x * (1.0f / 199.0f);
        pooledL[wv][(2 * pr + 1) * 2 + hg] = tot.y * (1.0f / 199.0f);
    }
    __syncthreads();

    {
        const int s2 = tid >> 6, f = tid & 63;
        const float v = pooledL[s2][f];
        const float4 wb = *(const float4*)(W_b1 + f * 4);
        float p0 = v * wb.x, p1 = v * wb.y, p2 = v * wb.z, p3 = v * wb.w;
#pragma unroll
        for (int off = 1; off < 64; off <<= 1) {
            p0 += __shfl_xor(p0, off, 64);
            p1 += __shfl_xor(p1, off, 64);
            p2 += __shfl_xor(p2, off, 64);
            p3 += __shfl_xor(p3, off, 64);
        }
        if (f == 0) {
            float* bp = bridge + (size_t)(n0 + s2) * 4;
            bp[0] = 1.0f / (1.0f + __expf(-(p0 + b_b1[0])));
            bp[1] = 1.0f / (1.0f + __expf(-(p1 + b_b1[1])));
            bp[2] = 1.0f / (1.0f + __expf(-(p2 + b_b1[2])));
            bp[3] = 1.0f / (1.0f + __expf(-(p3 + b_b1[3])));
        }
    }
}

// ============================================================================
// K234: forcast+floss (out) + segmentation (local) + attention + transformer.
// grid 256 = (b, 32-query chunk), 256 threads. Each block recomputes the
// per-b segmentation locally (~0.6us, replaces the separate k23 launch);
// ends/starts/nk written redundantly by all 8 blocks of a b (same values).
// hb[b,s] = bridge[s*32 + b] (scrambled). exp() select-guarded.
// ============================================================================
__global__ __launch_bounds__(256) void k234_seg_attn(
    const float* __restrict__ bridge, const float* __restrict__ imu_mask,
    const float* __restrict__ W_fc, const float* __restrict__ b_fc,
    const int* __restrict__ imu_len, float* __restrict__ out,
    int* __restrict__ ends_ws, int* __restrict__ starts_ws, int* __restrict__ nk_ws,
    const float* __restrict__ Wqkv, const float* __restrict__ Wo,
    const float* __restrict__ ln1_g, const float* __restrict__ ln1_b,
    const float* __restrict__ Wf1, const float* __restrict__ bf1,
    const float* __restrict__ Wf2, const float* __restrict__ bf2,
    const float* __restrict__ ln2_g, const float* __restrict__ ln2_b,
    const float* __restrict__ Wout, const float* __restrict__ bout,
    float* __restrict__ tr_ws)
{
    const int b = blockIdx.x >> 3;
    const int chunk = blockIdx.x & 7;
    const int tid = threadIdx.x;
    __shared__ float kv[256][8];
    __shared__ int sid[256];
    __shared__ float part[32][8][8];
    __shared__ float fl[256];
    __shared__ float sel[256];
    __shared__ float sp[256];
    __shared__ int pk[256];
    __shared__ int sc[2][256];
    __shared__ int kpl[256];

    // ---- stage K/V for all 256 keys (independent of segmentation) ----
    {
        const float4 h = *(const float4*)(bridge + (size_t)(tid * 32 + b) * 4);
#pragma unroll
        for (int e = 0; e < 4; ++e) {
            kv[tid][e]     = h.x * Wqkv[16 + e] + h.y * Wqkv[20 + e] + h.z * Wqkv[24 + e] + h.w * Wqkv[28 + e];
            kv[tid][4 + e] = h.x * Wqkv[32 + e] + h.y * Wqkv[36 + e] + h.z * Wqkv[40 + e] + h.w * Wqkv[44 + e];
        }
    }

    // ---- forcast + floss (n = b*256 + tid) ----
    {
        const int n = b * 256 + tid;
        float sh[4], cur[4];
#pragma unroll
        for (int j = 0; j < 4; ++j) {
            sh[j] = (tid == 0) ? 0.0f : bridge[(n - 1) * 4 + j];
            cur[j] = bridge[n * 4 + j];
        }
        const float fm = ((tid == 0) ? 0.0f : 1.0f) * imu_mask[n];
        float flv = 0.0f;
#pragma unroll
        for (int j = 0; j < 4; ++j) {
            float f = b_fc[j];
#pragma unroll
            for (int i = 0; i < 4; ++i) f = fmaf(sh[i], W_fc[i * 4 + j], f);
            out[OFF_FC + n * 4 + j] = f;
            const float d = (f - cur[j]) * fm;
            flv = fmaf(d, d, flv);
        }
        flv *= 0.25f;
        const bool lm = (tid >= 2) && (tid < 254);
        flv = (flv > 0.001f && lm) ? flv : 0.0f;
        out[OFF_FL + n] = flv;
        fl[tid] = flv;
        sp[tid] = 0.0f;
    }
    __syncthreads();

    // ---- segmentation (local) ----
    if (tid < 64) {                       // sel: windows of 4, first-max
        const int base = tid * 4;
        float m = fl[base]; int idx = 0;
#pragma unroll
        for (int i = 1; i < 4; ++i) { float v = fl[base + i]; if (v > m) { m = v; idx = i; } }
#pragma unroll
        for (int i = 0; i < 4; ++i) sel[base + i] = (i == idx) ? m : 0.0f;
    }
    __syncthreads();
    if (tid < 63) {                       // sel2 on sel[2:254)
        const int base = 2 + tid * 4;
        float m = sel[base]; int idx = 0;
#pragma unroll
        for (int i = 1; i < 4; ++i) { float v = sel[base + i]; if (v > m) { m = v; idx = i; } }
        sp[base + idx] = (m > 0.0f) ? 1.0f : 0.0f;
    }
    __syncthreads();
    int last = (int)rintf((float)imu_len[b] * (1.0f / 256.0f));  // half-even
    last = imin(imax(last, 2), 256);
    const int point = ((sp[tid] > 0.0f) && (tid < last)) ? 1 : 0;
    pk[tid] = point;
    __syncthreads();
    const int pnext = (tid < 255) ? pk[tid + 1] : 0;
    const int bnd = pnext | ((tid + 1 == last) ? 1 : 0);
    const int kept = (point && !bnd) ? 1 : 0;
    __syncthreads();
    sc[0][tid] = kept;
    __syncthreads();
    int src = 0;                          // Hillis-Steele inclusive scan
    for (int off = 1; off < 256; off <<= 1) {
        const int v = sc[src][tid] + ((tid >= off) ? sc[src][tid - off] : 0);
        sc[src ^ 1][tid] = v;
        __syncthreads();
        src ^= 1;
    }
    const int myid = sc[src][tid];
    sid[tid] = myid;
    const int nk = sc[src][255];
    if (kept) kpl[myid - 1] = tid;
    __syncthreads();
    if (tid < 130) {                      // redundant across the 8 b-blocks
        ends_ws[b * 130 + tid] = (tid < nk) ? kpl[tid] : last;
        starts_ws[b * 130 + tid] = (tid == 0) ? 0 : ((tid - 1 < nk) ? kpl[tid - 1] : last);
    }
    if (tid == 0) nk_ws[b] = nk;

    // ---- attention ----
    const int lq = tid & 31;
    const int jg = tid >> 5;
    const int sq = chunk * 32 + lq;
    {
        const float4 h = *(const float4*)(bridge + (size_t)(sq * 32 + b) * 4);
        float qv[4];
#pragma unroll
        for (int e = 0; e < 4; ++e)
            qv[e] = h.x * Wqkv[e] + h.y * Wqkv[4 + e] + h.z * Wqkv[8 + e] + h.w * Wqkv[12 + e];
        const bool vs = sq < last;
        const int ms = sid[sq];
        const float isq = 0.70710678118654752f;
        float m0 = -1e30f, l0 = 0.f, a00 = 0.f, a01 = 0.f;
        float m1 = -1e30f, l1 = 0.f, a10 = 0.f, a11 = 0.f;
#pragma unroll 4
        for (int jj = 0; jj < 32; ++jj) {
            const int j = jg * 32 + jj;
            const bool allowed = (j == sq) || (vs && (j < last) && (sid[j] == ms));
            const float sc0 = (qv[0] * kv[j][0] + qv[1] * kv[j][1]) * isq;
            const float sc1 = (qv[2] * kv[j][2] + qv[3] * kv[j][3]) * isq;
            {
                const float mn = allowed ? fmaxf(m0, sc0) : m0;
                const float c = __expf(m0 - mn);                      // arg <= 0 always
                const float e = allowed ? __expf(sc0 - mn) : 0.0f;    // select: no inf*0
                l0 = l0 * c + e; a00 = a00 * c + e * kv[j][4]; a01 = a01 * c + e * kv[j][5]; m0 = mn;
            }
            {
                const float mn = allowed ? fmaxf(m1, sc1) : m1;
                const float c = __expf(m1 - mn);
                const float e = allowed ? __expf(sc1 - mn) : 0.0f;
                l1 = l1 * c + e; a10 = a10 * c + e * kv[j][6]; a11 = a11 * c + e * kv[j][7]; m1 = mn;
            }
        }
        float* pp = part[lq][jg];
        pp[0] = m0; pp[1] = l0; pp[2] = a00; pp[3] = a01;
        pp[4] = m1; pp[5] = l1; pp[6] = a10; pp[7] = a11;
    }
    __syncthreads();
    if (tid < 32) {
        const int s = chunk * 32 + tid;
        float M0 = -1e30f, L0 = 0.f, A00 = 0.f, A01 = 0.f;
        float M1 = -1e30f, L1 = 0.f, A10 = 0.f, A11 = 0.f;
#pragma unroll
        for (int p = 0; p < 8; ++p) {
            const float* pp = part[tid][p];
            {
                const float mn = fmaxf(M0, pp[0]);
                const float c0 = __expf(M0 - mn), c1 = __expf(pp[0] - mn);   // args <= 0
                L0 = L0 * c0 + pp[1] * c1; A00 = A00 * c0 + pp[2] * c1; A01 = A01 * c0 + pp[3] * c1; M0 = mn;
            }
            {
                const float mn = fmaxf(M1, pp[4]);
                const float c0 = __expf(M1 - mn), c1 = __expf(pp[4] - mn);
                L1 = L1 * c0 + pp[5] * c1; A10 = A10 * c0 + pp[6] * c1; A11 = A11 * c0 + pp[7] * c1; M1 = mn;
            }
        }
        const float4 h = *(const float4*)(bridge + (size_t)(s * 32 + b) * 4);
        const float hb0 = h.x, hb1 = h.y, hb2 = h.z, hb3 = h.w;
        float ao[4] = {A00 / L0, A01 / L0, A10 / L1, A11 / L1};
        float x1[4];
#pragma unroll
        for (int jj = 0; jj < 4; ++jj)
            x1[jj] = ao[0] * Wo[jj] + ao[1] * Wo[4 + jj] + ao[2] * Wo[8 + jj] + ao[3] * Wo[12 + jj];
        x1[0] += hb0; x1[1] += hb1; x1[2] += hb2; x1[3] += hb3;
        float mean = 0.25f * (x1[0] + x1[1] + x1[2] + x1[3]);
        float var = 0.f;
#pragma unroll
        for (int i = 0; i < 4; ++i) { float d = x1[i] - mean; var += d * d; }
        var *= 0.25f;
        const float rs1 = rsqrtf(var + 1e-5f);
        float h1v[4];
#pragma unroll
        for (int i = 0; i < 4; ++i) h1v[i] = (x1[i] - mean) * rs1 * ln1_g[i] + ln1_b[i];
        float o2[4] = {bf2[0], bf2[1], bf2[2], bf2[3]};
#pragma unroll
        for (int kk = 0; kk < 16; ++kk) {
            float t = bf1[kk];
#pragma unroll
            for (int i = 0; i < 4; ++i) t = fmaf(h1v[i], Wf1[i * 16 + kk], t);
            t = fmaxf(t, 0.0f);
#pragma unroll
            for (int jj = 0; jj < 4; ++jj) o2[jj] = fmaf(t, Wf2[kk * 4 + jj], o2[jj]);
        }
        float x2[4];
#pragma unroll
        for (int i = 0; i < 4; ++i) x2[i] = h1v[i] + o2[i];
        float mean2 = 0.25f * (x2[0] + x2[1] + x2[2] + x2[3]);
        float var2 = 0.f;
#pragma unroll
        for (int i = 0; i < 4; ++i) { float d = x2[i] - mean2; var2 += d * d; }
        var2 *= 0.25f;
        const float rs2 = rsqrtf(var2 + 1e-5f);
        float h2v[4];
#pragma unroll
        for (int i = 0; i < 4; ++i) h2v[i] = (x2[i] - mean2) * rs2 * ln2_g[i] + ln2_b[i];
        float* tp = tr_ws + ((size_t)(b * 256 + s)) * 32;
#pragma unroll
        for (int mm = 0; mm < 32; ++mm)
            tp[mm] = bout[mm] + h2v[0] * Wout[mm] + h2v[1] * Wout[32 + mm]
                   + h2v[2] * Wout[64 + mm] + h2v[3] * Wout[96 + mm];
    }
}

// ============================================================================
// K5: atoms: atom_gen = (emb @ Wa + ba)*valid ; seg_interp gather from x
// grid (130, 32), 128 threads (120 active: d*20+i)
// ============================================================================
__global__ __launch_bounds__(128) void k5_atoms(
    const float* __restrict__ x, const float* __restrict__ tr_ws,
    const int* __restrict__ ends_ws, const int* __restrict__ starts_ws,
    const int* __restrict__ nk_ws,
    const float* __restrict__ Wa, const float* __restrict__ ba,
    float* __restrict__ out)
{
    const int a = blockIdx.x;
    const int b = blockIdx.y;
    const int tid = threadIdx.x;
    __shared__ float emb[32];
    const int e = ends_ws[b * 130 + a];
    const int st = starts_ws[b * 130 + a];
    const int nk = nk_ws[b];
    const float valid = (a <= nk) ? 1.0f : 0.0f;
    const int ec = imin(imax(e - 1, 0), 255);
    if (tid < 32) emb[tid] = tr_ws[((size_t)(b * 256 + ec)) * 32 + tid];
    __syncthreads();
    if (tid < 120) {
        float v = ba[tid];
#pragma unroll
        for (int f = 0; f < 32; ++f) v = fmaf(emb[f], Wa[f * 120 + tid], v);
        out[OFF_ATOM + ((size_t)(b * 130 + a)) * 120 + tid] = v * valid;
        const int d = tid / 20, i = tid % 20;
        const int ilen = (e - st) * 400;
        int idx = st * 400 + (i * ilen) / 20;
        idx = imin(imax(idx, 0), 102399);
        const int si = idx / 400, ti = idx % 400;
        const float px = x[(((size_t)b * 256 + si) * 6 + d) * 400 + ti];
        out[OFF_SEG + ((size_t)(b * 130 + a)) * 120 + tid] = px * valid;
    }
}

// ============================================================================
// K6: imu_gen GEMM: relu(bridge@Wd1+bd1) @ Wd2(64x2400) + bd2
// grid (256 n-tiles of 32, 10 m-tiles of 256), 256 threads, 8x4 micro-tile
// ============================================================================
__global__ __launch_bounds__(256) void k6_imu(
    const float* __restrict__ bridge, const float* __restrict__ Wd1,
    const float* __restrict__ bd1, const float* __restrict__ Wd2,
    const float* __restrict__ bd2, float* __restrict__ out)
{
    __shared__ float hl[64 * 32];     // [f][i]
    const int n0 = blockIdx.x * 32;
    const int mb = blockIdx.y;
    const int tid = threadIdx.x;
    for (int e = tid; e < 2048; e += 256) {
        const int f = e >> 5, i = e & 31;
        const float4 br = *(const float4*)(bridge + (size_t)(n0 + i) * 4);
        const float v = bd1[f] + br.x * Wd1[f] + br.y * Wd1[64 + f]
                      + br.z * Wd1[128 + f] + br.w * Wd1[192 + f];
        hl[f * 32 + i] = fmaxf(v, 0.0f);
    }
    __syncthreads();
    const int gm = tid & 63, gn = tid >> 6;
    const int m0 = mb * 256 + gm * 4;
    if (m0 >= 2400) return;
    float acc[8][4];
#pragma unroll
    for (int r = 0; r < 8; ++r)
#pragma unroll
        for (int c = 0; c < 4; ++c) acc[r][c] = 0.f;
#pragma unroll 4
    for (int f = 0; f < 64; ++f) {
        const float4 w4 = *(const float4*)&Wd2[(size_t)f * 2400 + m0];
        const float4 h0 = *(const float4*)&hl[f * 32 + gn * 8];
        const float4 h1 = *(const float4*)&hl[f * 32 + gn * 8 + 4];
        const float hv[8] = {h0.x, h0.y, h0.z, h0.w, h1.x, h1.y, h1.z, h1.w};
        const float wv[4] = {w4.x, w4.y, w4.z, w4.w};
#pragma unroll
        for (int r = 0; r < 8; ++r)
#pragma unroll
            for (int c = 0; c < 4; ++c) acc[r][c] = fmaf(hv[r], wv[c], acc[r][c]);
    }
    const float4 bb = *(const float4*)&bd2[m0];
#pragma unroll
    for (int r = 0; r < 8; ++r) {
        float4 o;
        o.x = acc[r][0] + bb.x; o.y = acc[r][1] + bb.y;
        o.z = acc[r][2] + bb.z; o.w = acc[r][3] + bb.w;
        *(float4*)&out[OFF_IMU + (size_t)(n0 + gn * 8 + r) * 2400 + m0] = o;
    }
}

// ============================================================================
extern "C" void kernel_launch(void* const* d_in, const int* in_sizes, int n_in,
                              void* d_out, int out_size, void* d_ws, size_t ws_size,
                              hipStream_t stream)
{
    const float* x        = (const float*)d_in[0];
    const float* imu_mask = (const float*)d_in[1];
    const int*   imu_len  = (const int*)  d_in[2];
    const float* conv_w   = (const float*)d_in[3];
    const float* conv_b   = (const float*)d_in[4];
    const float* W_b1     = (const float*)d_in[5];
    const float* b_b1     = (const float*)d_in[6];
    const float* W_fc     = (const float*)d_in[7];
    const float* b_fc     = (const float*)d_in[8];
    const float* Wqkv     = (const float*)d_in[9];
    const float* Wo       = (const float*)d_in[10];
    const float* ln1_g    = (const float*)d_in[11];
    const float* ln1_b    = (const float*)d_in[12];
    const float* Wf1      = (const float*)d_in[13];
    const float* bf1      = (const float*)d_in[14];
    const float* Wf2      = (const float*)d_in[15];
    const float* bf2      = (const float*)d_in[16];
    const float* ln2_g    = (const float*)d_in[17];
    const float* ln2_b    = (const float*)d_in[18];
    const float* Wout     = (const float*)d_in[19];
    const float* bout     = (const float*)d_in[20];
    const float* Wd1      = (const float*)d_in[21];
    const float* bd1      = (const float*)d_in[22];
    const float* Wd2      = (const float*)d_in[23];
    const float* bd2      = (const float*)d_in[24];
    const float* Wa       = (const float*)d_in[25];
    const float* ba       = (const float*)d_in[26];

    float* out = (float*)d_out;
    float* wsf = (float*)d_ws;
    int*   wsi = (int*)d_ws;

    float* bridge = wsf + WS_BRIDGE;
    float* tr_ws  = wsf + WS_TR;
    int* ends   = wsi + WS_ENDS;
    int* starts = wsi + WS_STARTS;
    int* nk     = wsi + WS_NK;

    k1_conv_bridge<<<2048, 256, 0, stream>>>(x, conv_w, conv_b, W_b1, b_b1, bridge);
    k234_seg_attn<<<256, 256, 0, stream>>>(bridge, imu_mask, W_fc, b_fc, imu_len,
                                           out, ends, starts, nk,
                                           Wqkv, Wo, ln1_g, ln1_b, Wf1, bf1,
                                           Wf2, bf2, ln2_g, ln2_b, Wout, bout, tr_ws);
    k5_atoms<<<dim3(130, 32), 128, 0, stream>>>(x, tr_ws, ends, starts, nk, Wa, ba, out);
    k6_imu<<<dim3(256, 10), 256, 0, stream>>>(bridge, Wd1, bd1, Wd2, bd2, out);
}